// Round 13
// baseline (153.974 us; speedup 1.0000x reference)
//
#include <hip/hip_runtime.h>

// R12: traffic reduction. R9-R11 all hit ~46-48us: 225MB of 16B-granular feat
// reads (40x re-read, one per depth) at ~4.9TB/s = L3 scattered-read ceiling;
// working set > 4MB/XCD L2; XCD banding by BEV row has no feat locality.
// Fix: materialize per-point fused values g[pos][c] (bf16, bin-sorted via the
// R4/R11-verified closed-form rank) in a produce pass that reads feat ONCE,
// then sum g over purely LINEAR pos ranges (constexpr BinStart). 77MB total
// vs 225MB+, no indirection, no atomics, empty bins written (no zero pass).

constexpr int D = 40, H = 32, W = 88, HW = H * W;       // 2816
constexpr int C = 128, NCAM = 6;
constexpr int BEV = 125, NBINS = BEV * BEV;             // 15625
constexpr int NPTS = D * HW;                            // 112640
constexpr int NCOLS = NCAM * HW;                        // 16896

typedef __attribute__((ext_vector_type(8))) unsigned short us8;
typedef __attribute__((ext_vector_type(4))) float f4;

__device__ __forceinline__ unsigned short f2bf(float x) {   // RNE
    unsigned u = __float_as_uint(x);
    return (unsigned short)((u + 0x7FFF + ((u >> 16) & 1)) >> 16);
}
__device__ __forceinline__ float b2f(unsigned short u) {
    return __uint_as_float(((unsigned)u) << 16);
}

__device__ __forceinline__ int ix_of(int w, float dep) {
    float gx = __fadd_rn(__fmul_rn(__fdiv_rn((float)w * dep, 3567.0f), 100.0f), -50.0f);
    return (int)__fdiv_rn(__fadd_rn(gx, 50.0f), 0.8f);
}
__device__ __forceinline__ int iy_of(int h, float dep) {
    float gy = __fadd_rn(__fmul_rn(__fdiv_rn((float)h * dep, 1271.0f), 100.0f), -50.0f);
    return (int)__fdiv_rn(__fadd_rn(gy, 50.0f), 0.8f);
}

// ---------------------------------------------------------------- constexpr tables
struct Tabs { short XP[D][126]; short YP[D][126]; };
constexpr Tabs make_tabs() {
    Tabs t{};
    for (int d = 0; d < D; ++d) {
        int dep = d + 2;
        int cntx[126] = {};
        for (int w = 0; w < W; ++w) {
            float gx = (float)(w * dep) / 3567.0f * 100.0f - 50.0f;
            int ix = (int)((gx + 50.0f) / 0.8f);
            if (ix < 125) cntx[ix]++;
        }
        t.XP[d][0] = 0;
        for (int X = 0; X < 125; ++X) t.XP[d][X + 1] = (short)(t.XP[d][X] + cntx[X]);
        int cnty[126] = {};
        for (int h = 0; h < H; ++h) {
            float gy = (float)(h * dep) / 1271.0f * 100.0f - 50.0f;
            int iy = (int)((gy + 50.0f) / 0.8f);
            if (iy < 125) cnty[iy]++;
        }
        t.YP[d][0] = 0;
        for (int Y = 0; Y < 125; ++Y) t.YP[d][Y + 1] = (short)(t.YP[d][Y] + cnty[Y]);
    }
    return t;
}
__device__ const Tabs g_tab = make_tabs();

// Per-bin global prefix (pos ranges) — emission order (iy, X, d, h, w).
struct BinStart { int s[NBINS + 1]; };
constexpr BinStart make_binstart() {
    BinStart B{};
    Tabs t = make_tabs();
    int run = 0;
    for (int iy = 0; iy < 125; ++iy) {
        int cnt[125] = {};
        for (int d = 0; d < D; ++d) {
            int yc = t.YP[d][iy + 1] - t.YP[d][iy];
            if (yc == 0) continue;
            for (int X = 0; X < 125; ++X)
                cnt[X] += (t.XP[d][X + 1] - t.XP[d][X]) * yc;
        }
        for (int X = 0; X < 125; ++X) { B.s[iy * 125 + X] = run; run += cnt[X]; }
    }
    B.s[NBINS] = run;
    return B;
}
__device__ const BinStart g_bs = make_binstart();

// Segments: (iy, X-range<=16, total count<=192); EVERY bin in exactly one seg
// (empty runs included -> sum kernel writes zeros; no zero pass, no atomics).
struct Segs2 { unsigned a[4096]; int n; };
constexpr Segs2 make_segs2() {
    Segs2 S{};
    Tabs t = make_tabs();
    int ns = 0;
    for (int iy = 0; iy < 125; ++iy) {
        int cnt[125] = {};
        for (int d = 0; d < D; ++d) {
            int yc = t.YP[d][iy + 1] - t.YP[d][iy];
            if (yc == 0) continue;
            for (int X = 0; X < 125; ++X)
                cnt[X] += (t.XP[d][X + 1] - t.XP[d][X]) * yc;
        }
        int X = 0;
        while (X < 125) {
            int X0 = X, run = 0;
            while (X < 125 && (X - X0) < 16 && (X == X0 || run + cnt[X] <= 192)) {
                run += cnt[X]; ++X;
            }
            S.a[ns++] = ((unsigned)iy << 16) | ((unsigned)X0 << 8) | (unsigned)X;
        }
    }
    S.n = ns;
    return S;
}
constexpr Segs2 g_ct2 = make_segs2();
constexpr int NSEG2 = g_ct2.n;
static_assert(NSEG2 > 0 && NSEG2 <= 4096, "seg table overflow");
__device__ const Segs2 g_segs2 = g_ct2;

// ---------------------------------------------------------------- D1: mega
// pack | softmax | fill pos_of (closed-form rank, verified R4/R11)
constexpr int PACK_BLOCKS = (C / 8) * (HW / 32);   // 1408
constexpr int SMAX_BLOCKS = NCOLS / 256;           // 66
constexpr int FILL_BLOCKS = NPTS / 256;            // 440
constexpr int MEGA_BLOCKS = PACK_BLOCKS + SMAX_BLOCKS + FILL_BLOCKS;

__global__ void __launch_bounds__(256) mega_kernel(
        const float* __restrict__ feat,     // [NCAM][C][HW]
        const float* __restrict__ logits,   // [NCAM][D][HW]
        float* __restrict__ probs_t,        // [(d<<12)|hw][8]
        unsigned short* __restrict__ feat_p,// [hw][c][8] bf16
        int* __restrict__ pos_of) {         // [d*HW+hw] -> pos or -1
    __shared__ __align__(16) float tile[NCAM * 8 * 37];
    int b = blockIdx.x, t = threadIdx.x;

    if (b < PACK_BLOCKS) {
        int c0  = (b / 88) * 8;
        int hw0 = (b % 88) * 32;
        int cq = t >> 5, hwL = t & 31;
#pragma unroll
        for (int n = 0; n < NCAM; ++n)
            tile[(n * 8 + cq) * 37 + hwL] =
                feat[((size_t)(n * C + c0 + cq)) * HW + hw0 + hwL];
        __syncthreads();
        int hl = t >> 3, cL = t & 7;
        us8 v;
#pragma unroll
        for (int n = 0; n < NCAM; ++n)
            v[n] = f2bf(tile[(n * 8 + cL) * 37 + hl]);
        v[6] = 0; v[7] = 0;
        *(us8*)(feat_p + ((size_t)(hw0 + hl) * C + (c0 + cL)) * 8) = v;

    } else if (b < PACK_BLOCKS + SMAX_BLOCKS) {
        int col = (b - PACK_BLOCKS) * 256 + t;       // < NCOLS exact
        int n  = col / HW;
        int hw = col - n * HW;
        const float* src = logits + ((size_t)n * D) * HW + hw;
        float v[D];
        float m = -3.402823466e+38f;
#pragma unroll
        for (int d = 0; d < D; ++d) {
            v[d] = src[(size_t)d * HW];
            m = fmaxf(m, v[d]);
        }
        float s = 0.f;
#pragma unroll
        for (int d = 0; d < D; ++d) { v[d] = expf(v[d] - m); s += v[d]; }
        float inv = 1.0f / s;
#pragma unroll
        for (int d = 0; d < D; ++d)
            probs_t[(size_t)((d << 12) | hw) * 8 + n] = v[d] * inv;

    } else {
        int pt = (b - PACK_BLOCKS - SMAX_BLOCKS) * 256 + t;   // < NPTS exact
        int d = pt / HW, hw = pt - d * HW, h = hw / W, w = hw - h * W;
        float dep = (float)(d + 2);
        int X = ix_of(w, dep), Y = iy_of(h, dep);
        int res = -1;
        if (X <= 124 && Y <= 124) {
            int pos = 0;
#pragma unroll 8
            for (int dd = 0; dd < D; ++dd) {          // entries before (bin,d)
                int ypY = g_tab.YP[dd][Y];
                int yc  = g_tab.YP[dd][Y + 1] - ypY;
                int xpX = g_tab.XP[dd][X];
                int xc  = g_tab.XP[dd][X + 1] - xpX;
                pos += ypY * g_tab.XP[dd][125] + yc * xpX
                     + ((dd < d) ? xc * yc : 0);
            }
            pos += (h - g_tab.YP[d][Y]) * (g_tab.XP[d][X + 1] - g_tab.XP[d][X])
                 + (w - g_tab.XP[d][X]);
            res = pos;
        }
        pos_of[pt] = res;
    }
}

// ---------------------------------------------------------------- D2: produce
// Block = hw, thread = c. ONE 16B feat load per thread (6 cams), then 40
// depths of: uniform pos + uniform probs + 6 FMA + one bf16 store (128B/wave,
// fire-and-forget). Feat read once: 5.8MB total (was 225MB).
__global__ void __launch_bounds__(128) produce_kernel(
        const unsigned short* __restrict__ feat_p,   // [hw][c][8]
        const float* __restrict__ probs_t,           // [(d<<12)|hw][8]
        const int* __restrict__ pos_of,              // [d*HW+hw]
        unsigned short* __restrict__ g) {            // [pos][C] bf16
    int hw = blockIdx.x;
    int c  = threadIdx.x;
    us8 f = *(const us8*)(feat_p + ((size_t)hw * C + c) * 8);
    float fc[6];
#pragma unroll
    for (int n = 0; n < NCAM; ++n) fc[n] = b2f(f[n]);

#pragma unroll 4
    for (int d = 0; d < D; ++d) {
        int pos = pos_of[d * HW + hw];               // wave-uniform
        if (pos < 0) continue;
        const float* pp = probs_t + ((size_t)((d << 12) | hw) << 3);
        float s = ((pp[0] * fc[0] + pp[1] * fc[1])
                 + (pp[2] * fc[2] + pp[3] * fc[3]))
                 + (pp[4] * fc[4] + pp[5] * fc[5]);
        g[(size_t)pos * C + c] = f2bf(s);
    }
}

// ---------------------------------------------------------------- D3: sum
// Block = segment (<=16 bins, one BEV row). Rows of g for a segment are one
// CONTIGUOUS region: wave wv sums pos parity wv for each bin (linear dword
// stream, 2 bf16/lane), stores to LDS tile once per bin, exactly-once
// coalesced flush. Empty bins store 0.
__global__ void __launch_bounds__(128) sum_kernel(
        const unsigned short* __restrict__ g,        // [pos][C] bf16
        float* __restrict__ out) {                   // [C][NBINS]
    __shared__ float T[2][16][128];                  // 16 KB
    unsigned da = g_segs2.a[blockIdx.x];
    int iy = da >> 16, X0 = (da >> 8) & 0xFF, X1 = da & 0xFF;
    int width = X1 - X0;
    int binbase = iy * BEV + X0;
    int t = threadIdx.x, l = t & 63, wv = t >> 6;

    for (int bl = 0; bl < width; ++bl) {
        int bs = g_bs.s[binbase + bl], be = g_bs.s[binbase + bl + 1];
        float a0 = 0.f, a1 = 0.f;
        for (int pos = bs + wv; pos < be; pos += 2) {
            unsigned v = *(const unsigned*)(g + (size_t)pos * C + 2 * l);
            a0 += b2f((unsigned short)(v & 0xFFFFu));
            a1 += b2f((unsigned short)(v >> 16));
        }
        T[wv][bl][2 * l]     = a0;
        T[wv][bl][2 * l + 1] = a1;
    }
    __syncthreads();

#pragma unroll
    for (int it = 0; it < 16; ++it) {                // 16 bl x 8 cc per iter
        int bl = t & 15, cc = it * 8 + (t >> 4);     // cc in [0,128)
        if (bl < width)
            out[(size_t)cc * NBINS + binbase + bl] = T[0][bl][cc] + T[1][bl][cc];
    }
}

// ---------------------------------------------------------------- launch
extern "C" void kernel_launch(void* const* d_in, const int* in_sizes, int n_in,
                              void* d_out, int out_size, void* d_ws, size_t ws_size,
                              hipStream_t stream) {
    const float* img_feat     = (const float*)d_in[0];
    const float* depth_logits = (const float*)d_in[1];
    float* out = (float*)d_out;

    char* p = (char*)d_ws;
    float*          probs_t = (float*)p;          p += (size_t)D * 4096 * 8 * 4;  // 5.24 MB
    unsigned short* feat_p  = (unsigned short*)p; p += (size_t)HW * C * 8 * 2;    // 5.77 MB
    int*            pos_of  = (int*)p;            p += (size_t)NPTS * 4;          // 450 KB
    unsigned short* g       = (unsigned short*)p; p += (size_t)NPTS * C * 2;      // 28.8 MB

    mega_kernel<<<MEGA_BLOCKS, 256, 0, stream>>>(
        img_feat, depth_logits, probs_t, feat_p, pos_of);
    produce_kernel<<<HW, 128, 0, stream>>>(feat_p, probs_t, pos_of, g);
    sum_kernel<<<NSEG2, 128, 0, stream>>>(g, out);
}

// Round 14
// 141.924 us; speedup vs baseline: 1.0849x; 1.0849x over previous
//
#include <hip/hip_runtime.h>

// R13: two dispatches, minimal kernel sum. R12 profile exposed the harness
// floor (ws 0xAA poison fill = 44us @ 6 TB/s + restores, per timed iter) --
// unattackable. Kernel-side: R11 gather structure but each lane handles TWO
// channels (c, c+64) -> wave-point-visits halve (225K->112K, same bytes;
// R9-R12 showed per-visit latency is the wall). Full-coverage segments
// (every bin in exactly one segment; slice = constexpr BinStart range) ->
// no d-split, no atomics, no zero-out phase.

constexpr int D = 40, H = 32, W = 88, HW = H * W;       // 2816
constexpr int C = 128, NCAM = 6;
constexpr int BEV = 125, NBINS = BEV * BEV;             // 15625
constexpr int NPTS = D * HW;                            // 112640
constexpr int NCOLS = NCAM * HW;                        // 16896

typedef __attribute__((ext_vector_type(8))) unsigned short us8;
typedef __attribute__((ext_vector_type(4))) float f4;

__device__ __forceinline__ unsigned short f2bf(float x) {   // RNE
    unsigned u = __float_as_uint(x);
    return (unsigned short)((u + 0x7FFF + ((u >> 16) & 1)) >> 16);
}
__device__ __forceinline__ float b2f(unsigned short u) {
    return __uint_as_float(((unsigned)u) << 16);
}

__device__ __forceinline__ int ix_of(int w, float dep) {
    float gx = __fadd_rn(__fmul_rn(__fdiv_rn((float)w * dep, 3567.0f), 100.0f), -50.0f);
    return (int)__fdiv_rn(__fadd_rn(gx, 50.0f), 0.8f);
}
__device__ __forceinline__ int iy_of(int h, float dep) {
    float gy = __fadd_rn(__fmul_rn(__fdiv_rn((float)h * dep, 1271.0f), 100.0f), -50.0f);
    return (int)__fdiv_rn(__fadd_rn(gy, 50.0f), 0.8f);
}

// ---------------------------------------------------------------- constexpr tables
struct Tabs { short XP[D][126]; short YP[D][126]; };
constexpr Tabs make_tabs() {
    Tabs t{};
    for (int d = 0; d < D; ++d) {
        int dep = d + 2;
        int cntx[126] = {};
        for (int w = 0; w < W; ++w) {
            float gx = (float)(w * dep) / 3567.0f * 100.0f - 50.0f;
            int ix = (int)((gx + 50.0f) / 0.8f);
            if (ix < 125) cntx[ix]++;
        }
        t.XP[d][0] = 0;
        for (int X = 0; X < 125; ++X) t.XP[d][X + 1] = (short)(t.XP[d][X] + cntx[X]);
        int cnty[126] = {};
        for (int h = 0; h < H; ++h) {
            float gy = (float)(h * dep) / 1271.0f * 100.0f - 50.0f;
            int iy = (int)((gy + 50.0f) / 0.8f);
            if (iy < 125) cnty[iy]++;
        }
        t.YP[d][0] = 0;
        for (int Y = 0; Y < 125; ++Y) t.YP[d][Y + 1] = (short)(t.YP[d][Y] + cnty[Y]);
    }
    return t;
}
__device__ const Tabs g_tab = make_tabs();

// Per-bin entry prefix (emission order iy, X, d, h, w) — verified R12.
struct BinStart { int s[NBINS + 1]; };
constexpr BinStart make_binstart() {
    BinStart B{};
    Tabs t = make_tabs();
    int run = 0;
    for (int iy = 0; iy < 125; ++iy) {
        int cnt[125] = {};
        for (int d = 0; d < D; ++d) {
            int yc = t.YP[d][iy + 1] - t.YP[d][iy];
            if (yc == 0) continue;
            for (int X = 0; X < 125; ++X)
                cnt[X] += (t.XP[d][X + 1] - t.XP[d][X]) * yc;
        }
        for (int X = 0; X < 125; ++X) { B.s[iy * 125 + X] = run; run += cnt[X]; }
    }
    B.s[NBINS] = run;
    return B;
}
__device__ const BinStart g_bs = make_binstart();

// Full-coverage segments (every bin in exactly one): iy<<16|X0<<8|X1.
struct Segs2 { unsigned a[4096]; int n; };
constexpr Segs2 make_segs2() {
    Segs2 S{};
    Tabs t = make_tabs();
    int ns = 0;
    for (int iy = 0; iy < 125; ++iy) {
        int cnt[125] = {};
        for (int d = 0; d < D; ++d) {
            int yc = t.YP[d][iy + 1] - t.YP[d][iy];
            if (yc == 0) continue;
            for (int X = 0; X < 125; ++X)
                cnt[X] += (t.XP[d][X + 1] - t.XP[d][X]) * yc;
        }
        int X = 0;
        while (X < 125) {
            int X0 = X, run = 0;
            while (X < 125 && (X - X0) < 16 && (X == X0 || run + cnt[X] <= 192)) {
                run += cnt[X]; ++X;
            }
            S.a[ns++] = ((unsigned)iy << 16) | ((unsigned)X0 << 8) | (unsigned)X;
        }
    }
    S.n = ns;
    return S;
}
constexpr Segs2 g_ct2 = make_segs2();
constexpr int NSEG2 = g_ct2.n;
static_assert(NSEG2 > 0 && NSEG2 <= 4096, "seg table overflow");
__device__ const Segs2 g_segs2 = g_ct2;

// ---------------------------------------------------------------- D1: mega
// pack | softmax | fill entries (closed-form bin-sorted rank, verified R11)
constexpr int PACK_BLOCKS = (C / 8) * (HW / 32);   // 1408
constexpr int SMAX_BLOCKS = NCOLS / 256;           // 66
constexpr int FILL_BLOCKS = NPTS / 256;            // 440
constexpr int MEGA_BLOCKS = PACK_BLOCKS + SMAX_BLOCKS + FILL_BLOCKS;

__global__ void __launch_bounds__(256) mega_kernel(
        const float* __restrict__ feat,     // [NCAM][C][HW]
        const float* __restrict__ logits,   // [NCAM][D][HW]
        float* __restrict__ probs_t,        // [(d<<12)|hw][8]
        unsigned short* __restrict__ feat_p,// [hw][c][8] bf16
        unsigned* __restrict__ entries) {   // [E] bin-sorted
    __shared__ __align__(16) float tile[NCAM * 8 * 37];
    int b = blockIdx.x, t = threadIdx.x;

    if (b < PACK_BLOCKS) {
        int c0  = (b / 88) * 8;
        int hw0 = (b % 88) * 32;
        int cq = t >> 5, hwL = t & 31;
#pragma unroll
        for (int n = 0; n < NCAM; ++n)
            tile[(n * 8 + cq) * 37 + hwL] =
                feat[((size_t)(n * C + c0 + cq)) * HW + hw0 + hwL];
        __syncthreads();
        int hl = t >> 3, cL = t & 7;
        us8 v;
#pragma unroll
        for (int n = 0; n < NCAM; ++n)
            v[n] = f2bf(tile[(n * 8 + cL) * 37 + hl]);
        v[6] = 0; v[7] = 0;
        *(us8*)(feat_p + ((size_t)(hw0 + hl) * C + (c0 + cL)) * 8) = v;

    } else if (b < PACK_BLOCKS + SMAX_BLOCKS) {
        int col = (b - PACK_BLOCKS) * 256 + t;       // < NCOLS exact
        int n  = col / HW;
        int hw = col - n * HW;
        const float* src = logits + ((size_t)n * D) * HW + hw;
        float v[D];
        float m = -3.402823466e+38f;
#pragma unroll
        for (int d = 0; d < D; ++d) {
            v[d] = src[(size_t)d * HW];
            m = fmaxf(m, v[d]);
        }
        float s = 0.f;
#pragma unroll
        for (int d = 0; d < D; ++d) { v[d] = expf(v[d] - m); s += v[d]; }
        float inv = 1.0f / s;
#pragma unroll
        for (int d = 0; d < D; ++d)
            probs_t[(size_t)((d << 12) | hw) * 8 + n] = v[d] * inv;

    } else {
        int pt = (b - PACK_BLOCKS - SMAX_BLOCKS) * 256 + t;   // < NPTS exact
        int d = pt / HW, hw = pt - d * HW, h = hw / W, w = hw - h * W;
        float dep = (float)(d + 2);
        int X = ix_of(w, dep), Y = iy_of(h, dep);
        if (X <= 124 && Y <= 124) {
            int pos = 0;
#pragma unroll 8
            for (int dd = 0; dd < D; ++dd) {          // entries before (bin,d)
                int ypY = g_tab.YP[dd][Y];
                int yc  = g_tab.YP[dd][Y + 1] - ypY;
                int xpX = g_tab.XP[dd][X];
                int xc  = g_tab.XP[dd][X + 1] - xpX;
                pos += ypY * g_tab.XP[dd][125] + yc * xpX
                     + ((dd < d) ? xc * yc : 0);
            }
            pos += (h - g_tab.YP[d][Y]) * (g_tab.XP[d][X + 1] - g_tab.XP[d][X])
                 + (w - g_tab.XP[d][X]);
            unsigned bin = (unsigned)(Y * BEV + X);
            entries[pos] = (bin << 18) | ((unsigned)d << 12) | (unsigned)hw;
        }
    }
}

// ---------------------------------------------------------------- D2: gather
// Block = segment. 128 thr = 2 waves; EACH WAVE covers all 128 channels
// (lane -> c=lane and c=lane+64), waves split the entry slice in halves.
// Per point: uniform entry load, TWO independent 16B feat loads, 12 FMA,
// register run-merge on wave-uniform bl. ILP-4 points. Flush exactly-once,
// coalesced; all bins covered -> no atomics, no out zeroing anywhere.
__global__ void __launch_bounds__(128, 4) gather_kernel(
        const unsigned short* __restrict__ feat_p,   // [hw][c][8] bf16
        const float* __restrict__ probs_t,           // [(d<<12)|hw][8] f32
        const unsigned* __restrict__ entries,
        float* __restrict__ out) {                   // [C][NBINS]
    __shared__ float T[2][16][130];                  // 16.3 KB
    unsigned da = g_segs2.a[blockIdx.x];
    int iy = da >> 16, X0 = (da >> 8) & 0xFF, X1 = da & 0xFF;
    int width = X1 - X0;
    int binbase = iy * BEV + X0;
    int t = threadIdx.x, lane = t & 63, wv = t >> 6;
    float* Tp = &T[wv][0][0];

    for (int i = lane; i < 16 * 130; i += 64) Tp[i] = 0.f;

    int bs = g_bs.s[binbase], be = g_bs.s[binbase + width];
    int P = be - bs;
    int half = (P + 1) >> 1;
    int beg = bs + (wv ? half : 0);
    int end = bs + (wv ? P : half);

    float r0 = 0.f, r1 = 0.f;
    int rbl = -1;
    int i = beg;
    for (; i + 4 <= end; i += 4) {
        unsigned pk[4];
#pragma unroll
        for (int j = 0; j < 4; ++j) pk[j] = entries[i + j];   // uniform loads
        us8 f0[4], f1[4];
#pragma unroll
        for (int j = 0; j < 4; ++j) {                         // 8 indep loads
            const unsigned short* fb = feat_p + ((size_t)(pk[j] & 0xFFFu) * C) * 8;
            f0[j] = *(const us8*)(fb + (unsigned)lane * 8);
            f1[j] = *(const us8*)(fb + (unsigned)(lane + 64) * 8);
        }
#pragma unroll
        for (int j = 0; j < 4; ++j) {
            const float* pp = probs_t + ((size_t)(pk[j] & 0x3FFFFu) << 3);
            float s0 = ((pp[0] * b2f(f0[j][0]) + pp[1] * b2f(f0[j][1]))
                      + (pp[2] * b2f(f0[j][2]) + pp[3] * b2f(f0[j][3])))
                      + (pp[4] * b2f(f0[j][4]) + pp[5] * b2f(f0[j][5]));
            float s1 = ((pp[0] * b2f(f1[j][0]) + pp[1] * b2f(f1[j][1]))
                      + (pp[2] * b2f(f1[j][2]) + pp[3] * b2f(f1[j][3])))
                      + (pp[4] * b2f(f1[j][4]) + pp[5] * b2f(f1[j][5]));
            int bl = (int)(pk[j] >> 18) - binbase;            // wave-uniform
            if (bl != rbl) {
                if (rbl >= 0) { Tp[rbl * 130 + lane] += r0; Tp[rbl * 130 + lane + 64] += r1; }
                rbl = bl; r0 = s0; r1 = s1;
            } else { r0 += s0; r1 += s1; }
        }
    }
    for (; i < end; ++i) {                                    // tail
        unsigned pk = entries[i];
        const unsigned short* fb = feat_p + ((size_t)(pk & 0xFFFu) * C) * 8;
        us8 f0 = *(const us8*)(fb + (unsigned)lane * 8);
        us8 f1 = *(const us8*)(fb + (unsigned)(lane + 64) * 8);
        const float* pp = probs_t + ((size_t)(pk & 0x3FFFFu) << 3);
        float s0 = ((pp[0] * b2f(f0[0]) + pp[1] * b2f(f0[1]))
                  + (pp[2] * b2f(f0[2]) + pp[3] * b2f(f0[3])))
                  + (pp[4] * b2f(f0[4]) + pp[5] * b2f(f0[5]));
        float s1 = ((pp[0] * b2f(f1[0]) + pp[1] * b2f(f1[1]))
                  + (pp[2] * b2f(f1[2]) + pp[3] * b2f(f1[3])))
                  + (pp[4] * b2f(f1[4]) + pp[5] * b2f(f1[5]));
        int bl = (int)(pk >> 18) - binbase;
        if (bl != rbl) {
            if (rbl >= 0) { Tp[rbl * 130 + lane] += r0; Tp[rbl * 130 + lane + 64] += r1; }
            rbl = bl; r0 = s0; r1 = s1;
        } else { r0 += s0; r1 += s1; }
    }
    if (rbl >= 0) { Tp[rbl * 130 + lane] += r0; Tp[rbl * 130 + lane + 64] += r1; }
    __syncthreads();

#pragma unroll
    for (int it = 0; it < 16; ++it) {                // 16 bl x 8 cc per iter
        int bl = t & 15, cc = it * 8 + (t >> 4);     // cc in [0,128)
        if (bl < width)
            out[(size_t)cc * NBINS + binbase + bl] = T[0][bl][cc] + T[1][bl][cc];
    }
}

// ---------------------------------------------------------------- launch
extern "C" void kernel_launch(void* const* d_in, const int* in_sizes, int n_in,
                              void* d_out, int out_size, void* d_ws, size_t ws_size,
                              hipStream_t stream) {
    const float* img_feat     = (const float*)d_in[0];
    const float* depth_logits = (const float*)d_in[1];
    float* out = (float*)d_out;

    char* p = (char*)d_ws;
    float*          probs_t = (float*)p;          p += (size_t)D * 4096 * 8 * 4;  // 5.24 MB
    unsigned short* feat_p  = (unsigned short*)p; p += (size_t)HW * C * 8 * 2;    // 5.77 MB
    unsigned*       entries = (unsigned*)p;       p += (size_t)NPTS * 4;          // 450 KB

    mega_kernel<<<MEGA_BLOCKS, 256, 0, stream>>>(
        img_feat, depth_logits, probs_t, feat_p, entries);
    gather_kernel<<<NSEG2, 128, 0, stream>>>(feat_p, probs_t, entries, out);
}